// Round 12
// baseline (373.746 us; speedup 1.0000x reference)
//
#include <hip/hip_runtime.h>

typedef unsigned int u32;
typedef _Float16 half_t;
typedef half_t h2    __attribute__((ext_vector_type(2)));
typedef half_t f16x8 __attribute__((ext_vector_type(8)));
typedef float  f32x4 __attribute__((ext_vector_type(4)));
typedef float  f32x2 __attribute__((ext_vector_type(2)));
typedef __fp16 fp16v2 __attribute__((ext_vector_type(2)));

#define NPTS 1048576

// Lessons encoded:
// 1) Never gate kernel defs / host launch on __has_builtin(amdgcn) -- false in
//    the host pass (rounds 1-2: silent 4.4x fallback).
// 2) __launch_bounds__ 2nd arg is an allocator FLOOR: (1024,8) forced spill
//    (round 5, 4x regression).  (1024,4) compiles this body to 64 VGPR clean.
// 3) Divergent table reads must come from LDS or iteration-ahead registers
//    (round 6: vol/planes from L2 -> latency-bound, 3x).
// 4) The allocator pins this kernel at 64 VGPR regardless of waves_per_eu
//    hints (R9 spilled f16 prefetch, R10 sank it).  f16 lines are compiler-
//    infeasible; fp8 lines + 2-instr decode stay.
// 5) In-wave interleave {issue LDS batch N+1 | FMA batch N} -> 123->109.5us (R8).
// 6) Row stride 144B (36 dw) put 16 random rows on only 8 bank offsets
//    ((36r)%32 = 4r%32) -> 1.86e7 conflict cycles.  33-dw rows (132B) are
//    coprime with 32 banks -> full 32-offset spread.  Same data, same math.
// (Round 11 was an infra failure -- container died twice; source unchanged,
//  bounds re-audited: all table reads end <= region boundaries.)

#if defined(__has_builtin)
#if __has_builtin(__builtin_amdgcn_update_dpp)
#define HAS_DPP 1
#endif
#endif
#ifndef HAS_DPP
#define HAS_DPP 0
#endif

// ---------------------------------------------------------------------------
// workspace layout (dwords)
//   lines (fp8, tap-split): 3*511 rows x 32 dw (128 B/row)           49,056 dw
//   table image (copied verbatim to LDS):                            37,328 dw
//     planes xy,yz f16: 2*400 rows x 33 dw (132 B/row, 1 dw pad)     26,400 dw
//     volume    f16:      125 rows x 33 dw                            4,125 dw
//     plane zx fp8:       400 rows x 17 dw (68 B/row, 1 dw pad)       6,800 dw
//     tail pad (uint4-align the copy)                                     3 dw
// ---------------------------------------------------------------------------
#define WS_LINE_DW   49056
#define TAB_PLN_DW   26400
#define TAB_VOL_END  30525          // 26400 + 4125
#define LDS_TOT_DW   37328          // 149,312 B
#define WS_TOTAL_DW  (WS_LINE_DW + LDS_TOT_DW)
#define WS_TOTAL_BYTES (WS_TOTAL_DW * 4)   // 345,536

// LDS byte offsets (within the 149,312 B table image)
#define LDS_YZ_B  52800             // 400 rows * 132 B
#define LDS_VOL_B 105600            // 26400 dw * 4
#define LDS_PZ8_B 122100            // 30525 dw * 4

__device__ __forceinline__ u32 pkh(float a, float b) {
    union { h2 h; u32 u; } r;
    r.h = (h2){(half_t)a, (half_t)b};
    return r.u;
}
__device__ __forceinline__ h2 pkrtz(float a, float b) {
    union { fp16v2 f; h2 h; } r;
    r.f = __builtin_amdgcn_cvt_pkrtz(a, b);
    return r.h;
}
// broadcast halves of a packed pair; folds into VOP3P op_sel on consumers
__device__ __forceinline__ h2 lo2(h2 v) { return __builtin_shufflevector(v, v, 0, 0); }
__device__ __forceinline__ h2 hi2(h2 v) { return __builtin_shufflevector(v, v, 1, 1); }

// fp8 byte-pair (word selected by HI) -> f16 pair (exact: e4m3 subset of f16)
template<bool HI>
__device__ __forceinline__ h2 c8h(u32 s) {
    f32x2 e = __builtin_amdgcn_cvt_pk_f32_fp8((int)s, HI);
    return pkrtz(e.x, e.y);
}
#if HAS_DPP
template<int CTRL>
__device__ __forceinline__ float dpp_bfly(float v) {
    int t = __builtin_amdgcn_update_dpp(0, __float_as_int(v), CTRL, 0xF, 0xF, false);
    return v + __int_as_float(t);
}
#endif

union U4 { uint4 v; u32 s[4]; };
union UH { uint4 v; h2 h[4]; };

// ---------------------------------------------------------------------------
// Prep: fp8 tap-split lines + [planes|vol|pzx] LDS image (33/17-dw rows)
// ---------------------------------------------------------------------------
__global__ __launch_bounds__(256) void ga_prep(
    const float* __restrict__ lx, const float* __restrict__ ly, const float* __restrict__ lz,
    const float* __restrict__ pxy, const float* __restrict__ pyz, const float* __restrict__ pzx,
    const float* __restrict__ vol, u32* __restrict__ ws)
{
    const int stride = gridDim.x * blockDim.x;
    for (int t = blockIdx.x * blockDim.x + threadIdx.x; t < WS_TOTAL_DW; t += stride) {
        if (t < WS_LINE_DW) {
            // fp8 lines, tap-split: dw d of row i0 = bytes (f0t0, f1t0, f0t1, f1t1)
            const int c  = t / 16352;           // 511*32
            const int r  = t - c * 16352;
            const int i0 = r >> 5;              // 0..510
            const int d  = r & 31;
            const float* L = (c == 0) ? lx : (c == 1) ? ly : lz;
            const int f0 = 2*d, f1 = 2*d + 1;
            int v = 0;
            v = __builtin_amdgcn_cvt_pk_fp8_f32(L[f0*512 + i0],     L[f1*512 + i0],     v, false);
            v = __builtin_amdgcn_cvt_pk_fp8_f32(L[f0*512 + i0 + 1], L[f1*512 + i0 + 1], v, true);
            ws[t] = (u32)v;
        } else {
            const int u = t - WS_LINE_DW;
            if (u < TAB_PLN_DW) {
                // planes xy,yz f16: [pp][row][33 dw] (1 dw pad)
                const int pp  = u / 13200;
                const int rr  = u - pp * 13200;
                const int row = rr / 33;
                const int d   = rr - row * 33;
                u32 v = 0;
                if (d < 32) {
                    const float* P = pp ? pyz : pxy;
                    const int f = 2*d;
                    v = pkh(P[f*400 + row], P[(f+1)*400 + row]);
                }
                ws[t] = v;
            } else if (u < TAB_VOL_END) {
                // volume f16: [vox][33 dw]
                const int r2  = u - TAB_PLN_DW;
                const int vox = r2 / 33;
                const int d   = r2 - vox * 33;
                u32 v = 0;
                if (d < 32) {
                    const int f = 2*d;
                    v = pkh(vol[f*125 + vox], vol[(f+1)*125 + vox]);
                }
                ws[t] = v;
            } else {
                // plane zx fp8: [row][17 dw] (1 dw pad); final 3 dw = tail pad
                const int r2  = u - TAB_VOL_END;
                const int row = r2 / 17;
                const int d   = r2 - row * 17;
                u32 v = 0;
                if (row < 400 && d < 16) {
                    const int f0 = d * 4;
                    int dw = 0;
                    dw = __builtin_amdgcn_cvt_pk_fp8_f32(pzx[(f0+0)*400+row], pzx[(f0+1)*400+row], dw, false);
                    dw = __builtin_amdgcn_cvt_pk_fp8_f32(pzx[(f0+2)*400+row], pzx[(f0+3)*400+row], dw, true);
                    v = (u32)dw;
                }
                ws[t] = v;
            }
        }
    }
}

// line setup: byte base + lerp weights for one channel
__device__ __forceinline__ void lsetup(float v, int cbase, int fg16,
                                       int& la, float& wm, float& ww)
{
    const float u   = fmaf(v, 0.5f, 0.5f);
    const float pos = u * 511.f;
    const float fi  = fminf(floorf(pos), 510.f);   // clamp needed: u can round to 1.0
    la = cbase + ((int)fi) * 128 + fg16;
    ww = pos - fi;
    wm = 1.f - ww;
}

// ---------------------------------------------------------------------------
// Main: lane = (point p = lane&15, feature group fg = lane>>4).
// All tables in LDS (149 KB, 1 block/CU, 33/17-dw bank-spread rows);
// lines fp8 from L2, depth-1 pipeline; cc body interleaves
// {issue LDS batch N+1 | FMA batch N}.
// ---------------------------------------------------------------------------
__global__ __launch_bounds__(1024, 4) void ga_main(
    const float* __restrict__ coords,
    const float* __restrict__ w1,
    const float* __restrict__ b1,
    const float* __restrict__ w2,
    const float* __restrict__ b2,
    const u32* __restrict__ ws,
    float* __restrict__ out)
{
    __shared__ alignas(16) u32 sP[LDS_TOT_DW];   // 149,312 B
    const int tid = threadIdx.x;
    {
        const uint4* src = (const uint4*)(ws + WS_LINE_DW);
        uint4* dst = (uint4*)sP;
        #pragma unroll
        for (int i = 0; i < 10; ++i) {
            int idx = tid + i * 1024;
            if (idx < 9332) dst[idx] = src[idx];
        }
    }

    const int lane = tid & 63;
    const int wave = tid >> 6;       // 0..15
    const int p    = lane & 15;
    const int fg   = lane >> 4;      // 0..3
    const int fg16 = fg << 4;
    const int fg8  = fg << 3;
    const int wgbase = blockIdx.x << 12;   // 4096 points per workgroup

    // w1 B-fragments (f16)
    f16x8 wfrag[4][2];
    #pragma unroll
    for (int t = 0; t < 4; ++t) {
        #pragma unroll
        for (int h = 0; h < 2; ++h) {
            const float* src = w1 + ((16*t + p)*64 + h*32 + fg*8);
            f16x8 w;
            #pragma unroll
            for (int e = 0; e < 8; ++e) w[e] = (half_t)src[e];
            wfrag[t][h] = w;
        }
    }
    float b1v[4], w2v[4];
    #pragma unroll
    for (int t = 0; t < 4; ++t) { b1v[t] = b1[16*t + p]; w2v[t] = w2[16*t + p]; }
    const float b2v = b2[0];

    const char* wsb = (const char*)ws;
    const char* spb = (const char*)sP;

    // pipeline prologue: first point's coords, line setup, line loads in flight
    const int pt0 = wgbase + (wave << 4) + p;
    float cx = coords[3*pt0 + 0];
    float cy = coords[3*pt0 + 1];
    float cz = coords[3*pt0 + 2];
    int la0, la1, la2;
    float lwm[3], lww[3];
    lsetup(cx, 0,      fg16, la0, lwm[0], lww[0]);
    lsetup(cy, 65408,  fg16, la1, lwm[1], lww[1]);
    lsetup(cz, 130816, fg16, la2, lwm[2], lww[2]);
    U4 X0, X1, Y0, Y1, Z0, Z1;
    X0.v = *(const uint4*)(wsb + la0);
    X1.v = *(const uint4*)(wsb + la0 + 64);
    Y0.v = *(const uint4*)(wsb + la1);
    Y1.v = *(const uint4*)(wsb + la1 + 64);
    Z0.v = *(const uint4*)(wsb + la2);
    Z1.v = *(const uint4*)(wsb + la2 + 64);

    __syncthreads();

    for (int g = wave; g < 256; g += 16) {
        const int pbase = wgbase + (g << 4);
        const int gn = (g + 16 < 256) ? g + 16 : g;
        const int ptn = wgbase + (gn << 4) + p;
        const float nx = coords[3*ptn + 0];
        const float ny = coords[3*ptn + 1];
        const float nz = coords[3*ptn + 2];

        // ---- per-point plane/vol setup (line setup done last iteration) ----
        int pidx[3], vidx[3];
        float pww[3], pwm[3], vww[3], vwm[3];
        {
            const float cc3[3] = {cx, cy, cz};
            #pragma unroll
            for (int c = 0; c < 3; ++c) {
                const float u = fmaf(cc3[c], 0.5f, 0.5f);
                float pq  = u * 19.f;
                float pi0 = fminf(floorf(pq), 18.f);
                pidx[c] = (int)pi0; pww[c] = pq - pi0; pwm[c] = 1.f - pww[c];
                float vq  = u * 4.f;
                float vi0 = fminf(floorf(vq), 3.f);
                vidx[c] = (int)vi0; vww[c] = vq - vi0; vwm[c] = 1.f - vww[c];
            }
        }
        // one mad per table; all corners are compile-time ds offsets.
        // 33-dw (132 B) rows: row -> bank offset row%32 (full 32-bank spread)
        const int axy = (pidx[1]*20 + pidx[0]) * 132 + fg16;
        const int ayz = (pidx[2]*20 + pidx[1]) * 132 + (LDS_YZ_B + fg16);
        const int azx = (pidx[0]*20 + pidx[2]) * 68  + (LDS_PZ8_B + fg8);
        const int av  = ((vidx[2]*5 + vidx[1])*5 + vidx[0]) * 132 + (LDS_VOL_B + fg16);

        // packed f16 weights (lo2/hi2 broadcasts fold into op_sel)
        const h2 wl0 = pkrtz(lwm[0], lww[0]);
        const h2 wl1 = pkrtz(lwm[1], lww[1]);
        const h2 wl2 = pkrtz(lwm[2], lww[2]);
        const h2 wxy0 = pkrtz(pwm[1]*pwm[0], pwm[1]*pww[0]);
        const h2 wxy1 = pkrtz(pww[1]*pwm[0], pww[1]*pww[0]);
        const h2 wyz0 = pkrtz(pwm[2]*pwm[1], pwm[2]*pww[1]);
        const h2 wyz1 = pkrtz(pww[2]*pwm[1], pww[2]*pww[1]);
        const h2 wzx0 = pkrtz(pwm[0]*pwm[2], pwm[0]*pww[2]);
        const h2 wzx1 = pkrtz(pww[0]*pwm[2], pww[0]*pww[2]);
        const float wy0 = vwm[1]*vwm[0], wy1 = vwm[1]*vww[0];
        const float wy2 = vww[1]*vwm[0], wy3 = vww[1]*vww[0];
        const h2 wv0 = pkrtz(vwm[2]*wy0, vwm[2]*wy1);
        const h2 wv1 = pkrtz(vwm[2]*wy2, vwm[2]*wy3);
        const h2 wv2 = pkrtz(vww[2]*wy0, vww[2]*wy1);
        const h2 wv3 = pkrtz(vww[2]*wy2, vww[2]*wy3);

        h2 comb[2][4];
        #pragma unroll
        for (int cc = 0; cc < 2; ++cc) {
            const int co = cc * 64;
            // ---- (1) issue volume LDS reads ----
            UH V[8];
            #pragma unroll
            for (int dz = 0; dz < 2; ++dz)
                #pragma unroll
                for (int dy = 0; dy < 2; ++dy)
                    #pragma unroll
                    for (int dx = 0; dx < 2; ++dx)
                        V[dz*4+dy*2+dx].v =
                            *(const uint4*)(spb + av + (dz*25+dy*5+dx)*132 + co);
            // ---- (2) line lerps: register-only, covers the vol ds_reads ----
            const U4& LXc = cc ? X1 : X0;
            const U4& LYc = cc ? Y1 : Y0;
            const U4& LZc = cc ? Z1 : Z0;
            h2 fx[4], fy[4], fz[4];
            #pragma unroll
            for (int i = 0; i < 4; ++i) {
                fx[i] = c8h<false>(LXc.s[i])*lo2(wl0) + c8h<true>(LXc.s[i])*hi2(wl0);
                fy[i] = c8h<false>(LYc.s[i])*lo2(wl1) + c8h<true>(LYc.s[i])*hi2(wl1);
                fz[i] = c8h<false>(LZc.s[i])*lo2(wl2) + c8h<true>(LZc.s[i])*hi2(wl2);
            }
            #pragma unroll
            for (int j = 0; j < 4; ++j) comb[cc][j] = fx[j]*fy[j]*fz[j];
            // ---- (3) issue plane-xy LDS reads ----
            UH r0, r1, r2, r3;
            r0.v = *(const uint4*)(spb + axy + co);
            r1.v = *(const uint4*)(spb + axy + 132 + co);
            r2.v = *(const uint4*)(spb + axy + 2640 + co);
            r3.v = *(const uint4*)(spb + axy + 2772 + co);
            // ---- (4) volume FMAs: cover the xy ds_reads ----
            #pragma unroll
            for (int j = 0; j < 4; ++j) {
                h2 s = V[0].h[j]*lo2(wv0) + V[1].h[j]*hi2(wv0)
                     + V[2].h[j]*lo2(wv1) + V[3].h[j]*hi2(wv1);
                s += V[4].h[j]*lo2(wv2) + V[5].h[j]*hi2(wv2)
                   + V[6].h[j]*lo2(wv3) + V[7].h[j]*hi2(wv3);
                comb[cc][j] += s;
            }
            // ---- (5) issue plane-yz LDS reads ----
            UH s0, s1, s2, s3;
            s0.v = *(const uint4*)(spb + ayz + co);
            s1.v = *(const uint4*)(spb + ayz + 132 + co);
            s2.v = *(const uint4*)(spb + ayz + 2640 + co);
            s3.v = *(const uint4*)(spb + ayz + 2772 + co);
            // ---- (6) plane-xy FMAs: cover the yz ds_reads ----
            #pragma unroll
            for (int j = 0; j < 4; ++j) {
                h2 pa = r0.h[j]*lo2(wxy0) + r1.h[j]*hi2(wxy0)
                      + r2.h[j]*lo2(wxy1) + r3.h[j]*hi2(wxy1);
                comb[cc][j] += pa * fz[j];
            }
            // ---- (7) issue plane-zx (fp8) LDS reads ----
            const int czo = cc * 32;
            const uint2 q0 = *(const uint2*)(spb + azx + czo);
            const uint2 q1 = *(const uint2*)(spb + azx + 68 + czo);
            const uint2 q2 = *(const uint2*)(spb + azx + 1360 + czo);
            const uint2 q3 = *(const uint2*)(spb + azx + 1428 + czo);
            // ---- (8) plane-yz FMAs: cover the zx ds_reads ----
            #pragma unroll
            for (int j = 0; j < 4; ++j) {
                h2 pa = s0.h[j]*lo2(wyz0) + s1.h[j]*hi2(wyz0)
                      + s2.h[j]*lo2(wyz1) + s3.h[j]*hi2(wyz1);
                comb[cc][j] += pa * fx[j];
            }
            // ---- (9) plane-zx decode + FMAs ----
            {
                h2 pa0 = c8h<false>(q0.x)*lo2(wzx0) + c8h<false>(q1.x)*hi2(wzx0)
                       + c8h<false>(q2.x)*lo2(wzx1) + c8h<false>(q3.x)*hi2(wzx1);
                h2 pa1 = c8h<true >(q0.x)*lo2(wzx0) + c8h<true >(q1.x)*hi2(wzx0)
                       + c8h<true >(q2.x)*lo2(wzx1) + c8h<true >(q3.x)*hi2(wzx1);
                h2 pa2 = c8h<false>(q0.y)*lo2(wzx0) + c8h<false>(q1.y)*hi2(wzx0)
                       + c8h<false>(q2.y)*lo2(wzx1) + c8h<false>(q3.y)*hi2(wzx1);
                h2 pa3 = c8h<true >(q0.y)*lo2(wzx0) + c8h<true >(q1.y)*hi2(wzx0)
                       + c8h<true >(q2.y)*lo2(wzx1) + c8h<true >(q3.y)*hi2(wzx1);
                comb[cc][0] += pa0 * fy[0];
                comb[cc][1] += pa1 * fy[1];
                comb[cc][2] += pa2 * fy[2];
                comb[cc][3] += pa3 * fy[3];
            }
        }

        // ---- pipeline: next iteration's line setup + loads, issued early ----
        int nla0, nla1, nla2;
        float nlwm[3], nlww[3];
        lsetup(nx, 0,      fg16, nla0, nlwm[0], nlww[0]);
        lsetup(ny, 65408,  fg16, nla1, nlwm[1], nlww[1]);
        lsetup(nz, 130816, fg16, nla2, nlwm[2], nlww[2]);
        U4 NX0, NX1, NY0, NY1, NZ0, NZ1;
        NX0.v = *(const uint4*)(wsb + nla0);
        NX1.v = *(const uint4*)(wsb + nla0 + 64);
        NY0.v = *(const uint4*)(wsb + nla1);
        NY1.v = *(const uint4*)(wsb + nla1 + 64);
        NZ0.v = *(const uint4*)(wsb + nla2);
        NZ1.v = *(const uint4*)(wsb + nla2 + 64);

        // ---- MLP layer 1 via f16 MFMA; comb is already the A-fragment ----
        union AF { f16x8 v; h2 h[4]; } A0, A1;
        #pragma unroll
        for (int j = 0; j < 4; ++j) { A0.h[j] = comb[0][j]; A1.h[j] = comb[1][j]; }
        f32x4 acc0 = {0.f,0.f,0.f,0.f};
        f32x4 acc1 = {0.f,0.f,0.f,0.f};
        f32x4 acc2 = {0.f,0.f,0.f,0.f};
        f32x4 acc3 = {0.f,0.f,0.f,0.f};
        acc0 = __builtin_amdgcn_mfma_f32_16x16x32_f16(A0.v, wfrag[0][0], acc0, 0, 0, 0);
        acc0 = __builtin_amdgcn_mfma_f32_16x16x32_f16(A1.v, wfrag[0][1], acc0, 0, 0, 0);
        acc1 = __builtin_amdgcn_mfma_f32_16x16x32_f16(A0.v, wfrag[1][0], acc1, 0, 0, 0);
        acc1 = __builtin_amdgcn_mfma_f32_16x16x32_f16(A1.v, wfrag[1][1], acc1, 0, 0, 0);
        acc2 = __builtin_amdgcn_mfma_f32_16x16x32_f16(A0.v, wfrag[2][0], acc2, 0, 0, 0);
        acc2 = __builtin_amdgcn_mfma_f32_16x16x32_f16(A1.v, wfrag[2][1], acc2, 0, 0, 0);
        acc3 = __builtin_amdgcn_mfma_f32_16x16x32_f16(A0.v, wfrag[3][0], acc3, 0, 0, 0);
        acc3 = __builtin_amdgcn_mfma_f32_16x16x32_f16(A1.v, wfrag[3][1], acc3, 0, 0, 0);
        // layer 2: relu + dot with w2; reduce across the 16 C-layout columns
        float sr[4];
        #pragma unroll
        for (int r = 0; r < 4; ++r) {
            float s = fmaxf(acc0[r] + b1v[0], 0.f) * w2v[0];
            s = fmaf(fmaxf(acc1[r] + b1v[1], 0.f), w2v[1], s);
            s = fmaf(fmaxf(acc2[r] + b1v[2], 0.f), w2v[2], s);
            s = fmaf(fmaxf(acc3[r] + b1v[3], 0.f), w2v[3], s);
            sr[r] = s;
        }
#if HAS_DPP
        #pragma unroll
        for (int r = 0; r < 4; ++r) {
            float s = sr[r];
            s = dpp_bfly<0xB1>(s);    // quad_perm [1,0,3,2]  (xor 1)
            s = dpp_bfly<0x4E>(s);    // quad_perm [2,3,0,1]  (xor 2)
            s = dpp_bfly<0x141>(s);   // row_half_mirror      (xor 7 within 8)
            s = dpp_bfly<0x140>(s);   // row_mirror           (xor 15 within 16)
            sr[r] = s;
        }
#else
        #pragma unroll
        for (int m = 1; m <= 8; m <<= 1) {
            #pragma unroll
            for (int r = 0; r < 4; ++r) sr[r] += __shfl_xor(sr[r], m, 64);
        }
#endif
        if (p == 0) {
            float4 o;
            o.x = sr[0] + b2v;
            o.y = sr[1] + b2v;
            o.z = sr[2] + b2v;
            o.w = sr[3] + b2v;
            *(float4*)(out + pbase + (fg << 2)) = o;
        }
        // rotate pipeline state
        cx = nx; cy = ny; cz = nz;
        lwm[0] = nlwm[0]; lwm[1] = nlwm[1]; lwm[2] = nlwm[2];
        lww[0] = nlww[0]; lww[1] = nlww[1]; lww[2] = nlww[2];
        X0 = NX0; X1 = NX1; Y0 = NY0; Y1 = NY1; Z0 = NZ0; Z1 = NZ1;
    }
}

// ---------------------------------------------------------------------------
// Fallback (only if ws_size is too small): slow but correct, thread-per-point.
// ---------------------------------------------------------------------------
__global__ __launch_bounds__(256) void ga_naive(
    const float* __restrict__ coords,
    const float* __restrict__ lx, const float* __restrict__ ly, const float* __restrict__ lz,
    const float* __restrict__ pxy, const float* __restrict__ pyz, const float* __restrict__ pzx,
    const float* __restrict__ vol,
    const float* __restrict__ w1, const float* __restrict__ b1,
    const float* __restrict__ w2, const float* __restrict__ b2,
    float* __restrict__ out)
{
    const int n = blockIdx.x * blockDim.x + threadIdx.x;
    if (n >= NPTS) return;
    int lidx[3], pidx[3], vidx[3];
    float lww[3], lwm[3], pww[3], pwm[3], vww[3], vwm[3];
    for (int c = 0; c < 3; ++c) {
        const float cv = coords[3*n + c];
        const float u = (cv + 1.f)*0.5f;
        float pos = fminf(fmaxf(u*511.f, 0.f), 511.f);
        float i0 = fminf(floorf(pos), 510.f);
        lidx[c] = (int)i0; lww[c] = pos - i0; lwm[c] = 1.f - lww[c];
        float pq = fminf(fmaxf(u*19.f, 0.f), 19.f);
        float pi0 = fminf(floorf(pq), 18.f);
        pidx[c] = (int)pi0; pww[c] = pq - pi0; pwm[c] = 1.f - pww[c];
        float vq = fminf(fmaxf(u*4.f, 0.f), 4.f);
        float vi0 = fminf(floorf(vq), 3.f);
        vidx[c] = (int)vi0; vww[c] = vq - vi0; vwm[c] = 1.f - vww[c];
    }
    float comb[64];
    for (int f = 0; f < 64; ++f) {
        const float fxv = lwm[0]*lx[f*512+lidx[0]] + lww[0]*lx[f*512+lidx[0]+1];
        const float fyv = lwm[1]*ly[f*512+lidx[1]] + lww[1]*ly[f*512+lidx[1]+1];
        const float fzv = lwm[2]*lz[f*512+lidx[2]] + lww[2]*lz[f*512+lidx[2]+1];
        const int bxy = f*400 + pidx[1]*20 + pidx[0];
        const float pxyv = pwm[1]*pwm[0]*pxy[bxy]    + pwm[1]*pww[0]*pxy[bxy+1]
                         + pww[1]*pwm[0]*pxy[bxy+20] + pww[1]*pww[0]*pxy[bxy+21];
        const int byz = f*400 + pidx[2]*20 + pidx[1];
        const float pyzv = pwm[2]*pwm[1]*pyz[byz]    + pwm[2]*pww[1]*pyz[byz+1]
                         + pww[2]*pwm[1]*pyz[byz+20] + pww[2]*pww[1]*pyz[byz+21];
        const int bzx = f*400 + pidx[0]*20 + pidx[2];
        const float pzxv = pwm[0]*pwm[2]*pzx[bzx]    + pwm[0]*pww[2]*pzx[bzx+1]
                         + pww[0]*pwm[2]*pzx[bzx+20] + pww[0]*pww[2]*pzx[bzx+21];
        const int bv = f*125 + (vidx[2]*5 + vidx[1])*5 + vidx[0];
        float vv = 0.f;
        for (int dz = 0; dz < 2; ++dz)
            for (int dy = 0; dy < 2; ++dy)
                for (int dx = 0; dx < 2; ++dx) {
                    const float w = (dz ? vww[2] : vwm[2]) * (dy ? vww[1] : vwm[1]) * (dx ? vww[0] : vwm[0]);
                    vv += w * vol[bv + dz*25 + dy*5 + dx];
                }
        comb[f] = fxv*fyv*fzv + pxyv*fzv + pyzv*fxv + pzxv*fyv + vv;
    }
    float o = b2[0];
    for (int gg = 0; gg < 64; ++gg) {
        float h = b1[gg];
        for (int f = 0; f < 64; ++f) h = fmaf(comb[f], w1[gg*64 + f], h);
        o = fmaf(fmaxf(h, 0.f), w2[gg], o);
    }
    out[n] = o;
}

extern "C" void kernel_launch(void* const* d_in, const int* in_sizes, int n_in,
                              void* d_out, int out_size, void* d_ws, size_t ws_size,
                              hipStream_t stream)
{
    const float* coords = (const float*)d_in[0];
    const float* lx  = (const float*)d_in[1];
    const float* ly  = (const float*)d_in[2];
    const float* lz  = (const float*)d_in[3];
    const float* pxy = (const float*)d_in[4];
    const float* pyz = (const float*)d_in[5];
    const float* pzx = (const float*)d_in[6];
    const float* vol = (const float*)d_in[7];
    const float* w1  = (const float*)d_in[8];
    const float* b1  = (const float*)d_in[9];
    const float* w2  = (const float*)d_in[10];
    const float* b2  = (const float*)d_in[11];
    float* out = (float*)d_out;
    if (ws_size >= (size_t)WS_TOTAL_BYTES) {
        u32* ws = (u32*)d_ws;
        ga_prep<<<dim3(350), dim3(256), 0, stream>>>(lx, ly, lz, pxy, pyz, pzx, vol, ws);
        ga_main<<<dim3(256), dim3(1024), 0, stream>>>(coords, w1, b1, w2, b2, ws, out);
    } else {
        ga_naive<<<dim3(4096), dim3(256), 0, stream>>>(coords, lx, ly, lz, pxy, pyz, pzx, vol,
                                                       w1, b1, w2, b2, out);
    }
}

// Round 13
// 195.305 us; speedup vs baseline: 1.9137x; 1.9137x over previous
//
#include <hip/hip_runtime.h>

typedef unsigned int u32;
typedef _Float16 half_t;
typedef half_t h2    __attribute__((ext_vector_type(2)));
typedef half_t f16x8 __attribute__((ext_vector_type(8)));
typedef float  f32x4 __attribute__((ext_vector_type(4)));
typedef float  f32x2 __attribute__((ext_vector_type(2)));
typedef __fp16 fp16v2 __attribute__((ext_vector_type(2)));

#define NPTS 1048576

// Lessons encoded:
// 1) Never gate kernel defs / host launch on __has_builtin(amdgcn) -- false in
//    the host pass (rounds 1-2: silent 4.4x fallback).
// 2) __launch_bounds__ 2nd arg is an allocator FLOOR: (1024,8) forced spill
//    (round 5, 4x regression).  (1024,4) compiles this body to 64 VGPR clean.
// 3) Divergent table reads must come from LDS or iteration-ahead registers
//    (round 6: vol/planes from L2 -> latency-bound, 3x).
// 4) The allocator pins this kernel at 64 VGPR (R9 spilled f16 prefetch,
//    R10 sank it).  fp8 lines + 2-instr decode stay.
// 5) In-wave interleave {issue LDS batch N+1 | FMA batch N} -> 123->109.5us (R8).
// 6) R12: 132-B (33-dw) rows eliminated bank conflicts (1.86e7 -> 32) but
//    broke 16-B alignment -> HW split every ds_read_b128 -> 3x SLOWER.
//    Alignment is a hard constraint.
// 7) THIS ROUND: 136-B (34-dw) rows are 8-B aligned, and 17 odd => 8-B phase
//    (17r+2fg+8cc+h) mod 16 covers all 16 phases from random rows.  Read each
//    16-B chunk as an 8-B-aligned uint2 PAIR (ds_read2_b64 / 2x b64 -- native,
//    no split).  pzx stays at R8's 72-B rows (9 odd: already 16-phase, aligned).

#if defined(__has_builtin)
#if __has_builtin(__builtin_amdgcn_update_dpp)
#define HAS_DPP 1
#endif
#endif
#ifndef HAS_DPP
#define HAS_DPP 0
#endif

// ---------------------------------------------------------------------------
// workspace layout (dwords)
//   lines (fp8, tap-split): 3*511 rows x 32 dw (128 B/row)           49,056 dw
//   table image (copied verbatim to LDS):                            38,652 dw
//     planes xy,yz f16: 2*400 rows x 34 dw (136 B/row, 2 dw pad)     27,200 dw
//     volume    f16:      125 rows x 34 dw                            4,250 dw
//     plane zx fp8:       400 rows x 18 dw (72 B/row, 2 dw pad)       7,200 dw
//     tail pad (uint4-align the copy)                                     2 dw
// ---------------------------------------------------------------------------
#define WS_LINE_DW   49056
#define TAB_PLN_DW   27200
#define TAB_VOL_END  31450          // 27200 + 4250
#define LDS_TOT_DW   38652          // 154,608 B (incl 2-dw tail pad)
#define WS_TOTAL_DW  (WS_LINE_DW + LDS_TOT_DW)
#define WS_TOTAL_BYTES (WS_TOTAL_DW * 4)   // 350,832

// LDS byte offsets (within the table image)
#define LDS_YZ_B  54400             // 400 rows * 136 B
#define LDS_VOL_B 108800            // 27,200 dw * 4
#define LDS_PZ8_B 125800            // 31,450 dw * 4

__device__ __forceinline__ u32 pkh(float a, float b) {
    union { h2 h; u32 u; } r;
    r.h = (h2){(half_t)a, (half_t)b};
    return r.u;
}
__device__ __forceinline__ h2 pkrtz(float a, float b) {
    union { fp16v2 f; h2 h; } r;
    r.f = __builtin_amdgcn_cvt_pkrtz(a, b);
    return r.h;
}
// broadcast halves of a packed pair; folds into VOP3P op_sel on consumers
__device__ __forceinline__ h2 lo2(h2 v) { return __builtin_shufflevector(v, v, 0, 0); }
__device__ __forceinline__ h2 hi2(h2 v) { return __builtin_shufflevector(v, v, 1, 1); }

// fp8 byte-pair (word selected by HI) -> f16 pair (exact: e4m3 subset of f16)
template<bool HI>
__device__ __forceinline__ h2 c8h(u32 s) {
    f32x2 e = __builtin_amdgcn_cvt_pk_f32_fp8((int)s, HI);
    return pkrtz(e.x, e.y);
}
#if HAS_DPP
template<int CTRL>
__device__ __forceinline__ float dpp_bfly(float v) {
    int t = __builtin_amdgcn_update_dpp(0, __float_as_int(v), CTRL, 0xF, 0xF, false);
    return v + __int_as_float(t);
}
#endif

union U4 { uint4 v; u32 s[4]; };
union UH { uint4 v; h2 h[4]; };

// 16-B logical read as two 8-B-aligned b64 accesses (rows are 8-B aligned,
// NOT 16-B aligned -- a uint4 read here would be a split misaligned b128, R12)
__device__ __forceinline__ UH ld16_8(const char* a) {
    const uint2 lo = *(const uint2*)(a);
    const uint2 hi = *(const uint2*)(a + 8);
    UH r;
    r.v = (uint4){lo.x, lo.y, hi.x, hi.y};
    return r;
}

// ---------------------------------------------------------------------------
// Prep: fp8 tap-split lines + [planes|vol|pzx] LDS image (34/18-dw rows)
// ---------------------------------------------------------------------------
__global__ __launch_bounds__(256) void ga_prep(
    const float* __restrict__ lx, const float* __restrict__ ly, const float* __restrict__ lz,
    const float* __restrict__ pxy, const float* __restrict__ pyz, const float* __restrict__ pzx,
    const float* __restrict__ vol, u32* __restrict__ ws)
{
    const int stride = gridDim.x * blockDim.x;
    for (int t = blockIdx.x * blockDim.x + threadIdx.x; t < WS_TOTAL_DW; t += stride) {
        if (t < WS_LINE_DW) {
            // fp8 lines, tap-split: dw d of row i0 = bytes (f0t0, f1t0, f0t1, f1t1)
            const int c  = t / 16352;           // 511*32
            const int r  = t - c * 16352;
            const int i0 = r >> 5;              // 0..510
            const int d  = r & 31;
            const float* L = (c == 0) ? lx : (c == 1) ? ly : lz;
            const int f0 = 2*d, f1 = 2*d + 1;
            int v = 0;
            v = __builtin_amdgcn_cvt_pk_fp8_f32(L[f0*512 + i0],     L[f1*512 + i0],     v, false);
            v = __builtin_amdgcn_cvt_pk_fp8_f32(L[f0*512 + i0 + 1], L[f1*512 + i0 + 1], v, true);
            ws[t] = (u32)v;
        } else {
            const int u = t - WS_LINE_DW;
            if (u < TAB_PLN_DW) {
                // planes xy,yz f16: [pp][row][34 dw] (2 dw pad)
                const int pp  = u / 13600;
                const int rr  = u - pp * 13600;
                const int row = rr / 34;
                const int d   = rr - row * 34;
                u32 v = 0;
                if (d < 32) {
                    const float* P = pp ? pyz : pxy;
                    const int f = 2*d;
                    v = pkh(P[f*400 + row], P[(f+1)*400 + row]);
                }
                ws[t] = v;
            } else if (u < TAB_VOL_END) {
                // volume f16: [vox][34 dw]
                const int r2  = u - TAB_PLN_DW;
                const int vox = r2 / 34;
                const int d   = r2 - vox * 34;
                u32 v = 0;
                if (d < 32) {
                    const int f = 2*d;
                    v = pkh(vol[f*125 + vox], vol[(f+1)*125 + vox]);
                }
                ws[t] = v;
            } else {
                // plane zx fp8: [row][18 dw] (2 dw pad); final 2 dw = tail pad
                const int r2  = u - TAB_VOL_END;
                const int row = r2 / 18;
                const int d   = r2 - row * 18;
                u32 v = 0;
                if (row < 400 && d < 16) {
                    const int f0 = d * 4;
                    int dw = 0;
                    dw = __builtin_amdgcn_cvt_pk_fp8_f32(pzx[(f0+0)*400+row], pzx[(f0+1)*400+row], dw, false);
                    dw = __builtin_amdgcn_cvt_pk_fp8_f32(pzx[(f0+2)*400+row], pzx[(f0+3)*400+row], dw, true);
                    v = (u32)dw;
                }
                ws[t] = v;
            }
        }
    }
}

// line setup: byte base + lerp weights for one channel
__device__ __forceinline__ void lsetup(float v, int cbase, int fg16,
                                       int& la, float& wm, float& ww)
{
    const float u   = fmaf(v, 0.5f, 0.5f);
    const float pos = u * 511.f;
    const float fi  = fminf(floorf(pos), 510.f);   // clamp needed: u can round to 1.0
    la = cbase + ((int)fi) * 128 + fg16;
    ww = pos - fi;
    wm = 1.f - ww;
}

// ---------------------------------------------------------------------------
// Main: lane = (point p = lane&15, feature group fg = lane>>4).
// All tables in LDS (154.6 KB, 1 block/CU); plane/vol rows 136 B -> 16-phase
// bank spread, read as 8-B-aligned b64 pairs; pzx 72-B rows (R8).  Lines fp8
// from L2, depth-1 pipeline; cc body interleaves {LDS batch N+1 | FMA batch N}.
// ---------------------------------------------------------------------------
__global__ __launch_bounds__(1024, 4) void ga_main(
    const float* __restrict__ coords,
    const float* __restrict__ w1,
    const float* __restrict__ b1,
    const float* __restrict__ w2,
    const float* __restrict__ b2,
    const u32* __restrict__ ws,
    float* __restrict__ out)
{
    __shared__ alignas(16) u32 sP[LDS_TOT_DW];   // 154,608 B
    const int tid = threadIdx.x;
    {
        const uint4* src = (const uint4*)(ws + WS_LINE_DW);
        uint4* dst = (uint4*)sP;
        #pragma unroll
        for (int i = 0; i < 10; ++i) {
            int idx = tid + i * 1024;
            if (idx < 9663) dst[idx] = src[idx];
        }
    }

    const int lane = tid & 63;
    const int wave = tid >> 6;       // 0..15
    const int p    = lane & 15;
    const int fg   = lane >> 4;      // 0..3
    const int fg16 = fg << 4;
    const int fg8  = fg << 3;
    const int wgbase = blockIdx.x << 12;   // 4096 points per workgroup

    // w1 B-fragments (f16)
    f16x8 wfrag[4][2];
    #pragma unroll
    for (int t = 0; t < 4; ++t) {
        #pragma unroll
        for (int h = 0; h < 2; ++h) {
            const float* src = w1 + ((16*t + p)*64 + h*32 + fg*8);
            f16x8 w;
            #pragma unroll
            for (int e = 0; e < 8; ++e) w[e] = (half_t)src[e];
            wfrag[t][h] = w;
        }
    }
    float b1v[4], w2v[4];
    #pragma unroll
    for (int t = 0; t < 4; ++t) { b1v[t] = b1[16*t + p]; w2v[t] = w2[16*t + p]; }
    const float b2v = b2[0];

    const char* wsb = (const char*)ws;
    const char* spb = (const char*)sP;

    // pipeline prologue: first point's coords, line setup, line loads in flight
    const int pt0 = wgbase + (wave << 4) + p;
    float cx = coords[3*pt0 + 0];
    float cy = coords[3*pt0 + 1];
    float cz = coords[3*pt0 + 2];
    int la0, la1, la2;
    float lwm[3], lww[3];
    lsetup(cx, 0,      fg16, la0, lwm[0], lww[0]);
    lsetup(cy, 65408,  fg16, la1, lwm[1], lww[1]);
    lsetup(cz, 130816, fg16, la2, lwm[2], lww[2]);
    U4 X0, X1, Y0, Y1, Z0, Z1;
    X0.v = *(const uint4*)(wsb + la0);
    X1.v = *(const uint4*)(wsb + la0 + 64);
    Y0.v = *(const uint4*)(wsb + la1);
    Y1.v = *(const uint4*)(wsb + la1 + 64);
    Z0.v = *(const uint4*)(wsb + la2);
    Z1.v = *(const uint4*)(wsb + la2 + 64);

    __syncthreads();

    for (int g = wave; g < 256; g += 16) {
        const int pbase = wgbase + (g << 4);
        const int gn = (g + 16 < 256) ? g + 16 : g;
        const int ptn = wgbase + (gn << 4) + p;
        const float nx = coords[3*ptn + 0];
        const float ny = coords[3*ptn + 1];
        const float nz = coords[3*ptn + 2];

        // ---- per-point plane/vol setup (line setup done last iteration) ----
        int pidx[3], vidx[3];
        float pww[3], pwm[3], vww[3], vwm[3];
        {
            const float cc3[3] = {cx, cy, cz};
            #pragma unroll
            for (int c = 0; c < 3; ++c) {
                const float u = fmaf(cc3[c], 0.5f, 0.5f);
                float pq  = u * 19.f;
                float pi0 = fminf(floorf(pq), 18.f);
                pidx[c] = (int)pi0; pww[c] = pq - pi0; pwm[c] = 1.f - pww[c];
                float vq  = u * 4.f;
                float vi0 = fminf(floorf(vq), 3.f);
                vidx[c] = (int)vi0; vww[c] = vq - vi0; vwm[c] = 1.f - vww[c];
            }
        }
        // one mad per table; corners are compile-time offsets.
        // 34-dw (136 B) rows, 8-B aligned; 17 odd -> full 16-phase spread
        const int axy = (pidx[1]*20 + pidx[0]) * 136 + fg16;
        const int ayz = (pidx[2]*20 + pidx[1]) * 136 + (LDS_YZ_B + fg16);
        const int azx = (pidx[0]*20 + pidx[2]) * 72  + (LDS_PZ8_B + fg8);
        const int av  = ((vidx[2]*5 + vidx[1])*5 + vidx[0]) * 136 + (LDS_VOL_B + fg16);

        // packed f16 weights (lo2/hi2 broadcasts fold into op_sel)
        const h2 wl0 = pkrtz(lwm[0], lww[0]);
        const h2 wl1 = pkrtz(lwm[1], lww[1]);
        const h2 wl2 = pkrtz(lwm[2], lww[2]);
        const h2 wxy0 = pkrtz(pwm[1]*pwm[0], pwm[1]*pww[0]);
        const h2 wxy1 = pkrtz(pww[1]*pwm[0], pww[1]*pww[0]);
        const h2 wyz0 = pkrtz(pwm[2]*pwm[1], pwm[2]*pww[1]);
        const h2 wyz1 = pkrtz(pww[2]*pwm[1], pww[2]*pww[1]);
        const h2 wzx0 = pkrtz(pwm[0]*pwm[2], pwm[0]*pww[2]);
        const h2 wzx1 = pkrtz(pww[0]*pwm[2], pww[0]*pww[2]);
        const float wy0 = vwm[1]*vwm[0], wy1 = vwm[1]*vww[0];
        const float wy2 = vww[1]*vwm[0], wy3 = vww[1]*vww[0];
        const h2 wv0 = pkrtz(vwm[2]*wy0, vwm[2]*wy1);
        const h2 wv1 = pkrtz(vwm[2]*wy2, vwm[2]*wy3);
        const h2 wv2 = pkrtz(vww[2]*wy0, vww[2]*wy1);
        const h2 wv3 = pkrtz(vww[2]*wy2, vww[2]*wy3);

        h2 comb[2][4];
        #pragma unroll
        for (int cc = 0; cc < 2; ++cc) {
            const int co = cc * 64;
            // ---- (1) issue volume LDS reads (b64 pairs) ----
            UH V[8];
            #pragma unroll
            for (int dz = 0; dz < 2; ++dz)
                #pragma unroll
                for (int dy = 0; dy < 2; ++dy)
                    #pragma unroll
                    for (int dx = 0; dx < 2; ++dx)
                        V[dz*4+dy*2+dx] =
                            ld16_8(spb + av + (dz*25+dy*5+dx)*136 + co);
            // ---- (2) line lerps: register-only, covers the vol ds_reads ----
            const U4& LXc = cc ? X1 : X0;
            const U4& LYc = cc ? Y1 : Y0;
            const U4& LZc = cc ? Z1 : Z0;
            h2 fx[4], fy[4], fz[4];
            #pragma unroll
            for (int i = 0; i < 4; ++i) {
                fx[i] = c8h<false>(LXc.s[i])*lo2(wl0) + c8h<true>(LXc.s[i])*hi2(wl0);
                fy[i] = c8h<false>(LYc.s[i])*lo2(wl1) + c8h<true>(LYc.s[i])*hi2(wl1);
                fz[i] = c8h<false>(LZc.s[i])*lo2(wl2) + c8h<true>(LZc.s[i])*hi2(wl2);
            }
            #pragma unroll
            for (int j = 0; j < 4; ++j) comb[cc][j] = fx[j]*fy[j]*fz[j];
            // ---- (3) issue plane-xy LDS reads ----
            UH r0 = ld16_8(spb + axy + co);
            UH r1 = ld16_8(spb + axy + 136 + co);
            UH r2 = ld16_8(spb + axy + 2720 + co);
            UH r3 = ld16_8(spb + axy + 2856 + co);
            // ---- (4) volume FMAs: cover the xy ds_reads ----
            #pragma unroll
            for (int j = 0; j < 4; ++j) {
                h2 s = V[0].h[j]*lo2(wv0) + V[1].h[j]*hi2(wv0)
                     + V[2].h[j]*lo2(wv1) + V[3].h[j]*hi2(wv1);
                s += V[4].h[j]*lo2(wv2) + V[5].h[j]*hi2(wv2)
                   + V[6].h[j]*lo2(wv3) + V[7].h[j]*hi2(wv3);
                comb[cc][j] += s;
            }
            // ---- (5) issue plane-yz LDS reads ----
            UH s0 = ld16_8(spb + ayz + co);
            UH s1 = ld16_8(spb + ayz + 136 + co);
            UH s2 = ld16_8(spb + ayz + 2720 + co);
            UH s3 = ld16_8(spb + ayz + 2856 + co);
            // ---- (6) plane-xy FMAs: cover the yz ds_reads ----
            #pragma unroll
            for (int j = 0; j < 4; ++j) {
                h2 pa = r0.h[j]*lo2(wxy0) + r1.h[j]*hi2(wxy0)
                      + r2.h[j]*lo2(wxy1) + r3.h[j]*hi2(wxy1);
                comb[cc][j] += pa * fz[j];
            }
            // ---- (7) issue plane-zx (fp8) LDS reads ----
            const int czo = cc * 32;
            const uint2 q0 = *(const uint2*)(spb + azx + czo);
            const uint2 q1 = *(const uint2*)(spb + azx + 72 + czo);
            const uint2 q2 = *(const uint2*)(spb + azx + 1440 + czo);
            const uint2 q3 = *(const uint2*)(spb + azx + 1512 + czo);
            // ---- (8) plane-yz FMAs: cover the zx ds_reads ----
            #pragma unroll
            for (int j = 0; j < 4; ++j) {
                h2 pa = s0.h[j]*lo2(wyz0) + s1.h[j]*hi2(wyz0)
                      + s2.h[j]*lo2(wyz1) + s3.h[j]*hi2(wyz1);
                comb[cc][j] += pa * fx[j];
            }
            // ---- (9) plane-zx decode + FMAs ----
            {
                h2 pa0 = c8h<false>(q0.x)*lo2(wzx0) + c8h<false>(q1.x)*hi2(wzx0)
                       + c8h<false>(q2.x)*lo2(wzx1) + c8h<false>(q3.x)*hi2(wzx1);
                h2 pa1 = c8h<true >(q0.x)*lo2(wzx0) + c8h<true >(q1.x)*hi2(wzx0)
                       + c8h<true >(q2.x)*lo2(wzx1) + c8h<true >(q3.x)*hi2(wzx1);
                h2 pa2 = c8h<false>(q0.y)*lo2(wzx0) + c8h<false>(q1.y)*hi2(wzx0)
                       + c8h<false>(q2.y)*lo2(wzx1) + c8h<false>(q3.y)*hi2(wzx1);
                h2 pa3 = c8h<true >(q0.y)*lo2(wzx0) + c8h<true >(q1.y)*hi2(wzx0)
                       + c8h<true >(q2.y)*lo2(wzx1) + c8h<true >(q3.y)*hi2(wzx1);
                comb[cc][0] += pa0 * fy[0];
                comb[cc][1] += pa1 * fy[1];
                comb[cc][2] += pa2 * fy[2];
                comb[cc][3] += pa3 * fy[3];
            }
        }

        // ---- pipeline: next iteration's line setup + loads, issued early ----
        int nla0, nla1, nla2;
        float nlwm[3], nlww[3];
        lsetup(nx, 0,      fg16, nla0, nlwm[0], nlww[0]);
        lsetup(ny, 65408,  fg16, nla1, nlwm[1], nlww[1]);
        lsetup(nz, 130816, fg16, nla2, nlwm[2], nlww[2]);
        U4 NX0, NX1, NY0, NY1, NZ0, NZ1;
        NX0.v = *(const uint4*)(wsb + nla0);
        NX1.v = *(const uint4*)(wsb + nla0 + 64);
        NY0.v = *(const uint4*)(wsb + nla1);
        NY1.v = *(const uint4*)(wsb + nla1 + 64);
        NZ0.v = *(const uint4*)(wsb + nla2);
        NZ1.v = *(const uint4*)(wsb + nla2 + 64);

        // ---- MLP layer 1 via f16 MFMA; comb is already the A-fragment ----
        union AF { f16x8 v; h2 h[4]; } A0, A1;
        #pragma unroll
        for (int j = 0; j < 4; ++j) { A0.h[j] = comb[0][j]; A1.h[j] = comb[1][j]; }
        f32x4 acc0 = {0.f,0.f,0.f,0.f};
        f32x4 acc1 = {0.f,0.f,0.f,0.f};
        f32x4 acc2 = {0.f,0.f,0.f,0.f};
        f32x4 acc3 = {0.f,0.f,0.f,0.f};
        acc0 = __builtin_amdgcn_mfma_f32_16x16x32_f16(A0.v, wfrag[0][0], acc0, 0, 0, 0);
        acc0 = __builtin_amdgcn_mfma_f32_16x16x32_f16(A1.v, wfrag[0][1], acc0, 0, 0, 0);
        acc1 = __builtin_amdgcn_mfma_f32_16x16x32_f16(A0.v, wfrag[1][0], acc1, 0, 0, 0);
        acc1 = __builtin_amdgcn_mfma_f32_16x16x32_f16(A1.v, wfrag[1][1], acc1, 0, 0, 0);
        acc2 = __builtin_amdgcn_mfma_f32_16x16x32_f16(A0.v, wfrag[2][0], acc2, 0, 0, 0);
        acc2 = __builtin_amdgcn_mfma_f32_16x16x32_f16(A1.v, wfrag[2][1], acc2, 0, 0, 0);
        acc3 = __builtin_amdgcn_mfma_f32_16x16x32_f16(A0.v, wfrag[3][0], acc3, 0, 0, 0);
        acc3 = __builtin_amdgcn_mfma_f32_16x16x32_f16(A1.v, wfrag[3][1], acc3, 0, 0, 0);
        // layer 2: relu + dot with w2; reduce across the 16 C-layout columns
        float sr[4];
        #pragma unroll
        for (int r = 0; r < 4; ++r) {
            float s = fmaxf(acc0[r] + b1v[0], 0.f) * w2v[0];
            s = fmaf(fmaxf(acc1[r] + b1v[1], 0.f), w2v[1], s);
            s = fmaf(fmaxf(acc2[r] + b1v[2], 0.f), w2v[2], s);
            s = fmaf(fmaxf(acc3[r] + b1v[3], 0.f), w2v[3], s);
            sr[r] = s;
        }
#if HAS_DPP
        #pragma unroll
        for (int r = 0; r < 4; ++r) {
            float s = sr[r];
            s = dpp_bfly<0xB1>(s);    // quad_perm [1,0,3,2]  (xor 1)
            s = dpp_bfly<0x4E>(s);    // quad_perm [2,3,0,1]  (xor 2)
            s = dpp_bfly<0x141>(s);   // row_half_mirror      (xor 7 within 8)
            s = dpp_bfly<0x140>(s);   // row_mirror           (xor 15 within 16)
            sr[r] = s;
        }
#else
        #pragma unroll
        for (int m = 1; m <= 8; m <<= 1) {
            #pragma unroll
            for (int r = 0; r < 4; ++r) sr[r] += __shfl_xor(sr[r], m, 64);
        }
#endif
        if (p == 0) {
            float4 o;
            o.x = sr[0] + b2v;
            o.y = sr[1] + b2v;
            o.z = sr[2] + b2v;
            o.w = sr[3] + b2v;
            *(float4*)(out + pbase + (fg << 2)) = o;
        }
        // rotate pipeline state
        cx = nx; cy = ny; cz = nz;
        lwm[0] = nlwm[0]; lwm[1] = nlwm[1]; lwm[2] = nlwm[2];
        lww[0] = nlww[0]; lww[1] = nlww[1]; lww[2] = nlww[2];
        X0 = NX0; X1 = NX1; Y0 = NY0; Y1 = NY1; Z0 = NZ0; Z1 = NZ1;
    }
}

// ---------------------------------------------------------------------------
// Fallback (only if ws_size is too small): slow but correct, thread-per-point.
// ---------------------------------------------------------------------------
__global__ __launch_bounds__(256) void ga_naive(
    const float* __restrict__ coords,
    const float* __restrict__ lx, const float* __restrict__ ly, const float* __restrict__ lz,
    const float* __restrict__ pxy, const float* __restrict__ pyz, const float* __restrict__ pzx,
    const float* __restrict__ vol,
    const float* __restrict__ w1, const float* __restrict__ b1,
    const float* __restrict__ w2, const float* __restrict__ b2,
    float* __restrict__ out)
{
    const int n = blockIdx.x * blockDim.x + threadIdx.x;
    if (n >= NPTS) return;
    int lidx[3], pidx[3], vidx[3];
    float lww[3], lwm[3], pww[3], pwm[3], vww[3], vwm[3];
    for (int c = 0; c < 3; ++c) {
        const float cv = coords[3*n + c];
        const float u = (cv + 1.f)*0.5f;
        float pos = fminf(fmaxf(u*511.f, 0.f), 511.f);
        float i0 = fminf(floorf(pos), 510.f);
        lidx[c] = (int)i0; lww[c] = pos - i0; lwm[c] = 1.f - lww[c];
        float pq = fminf(fmaxf(u*19.f, 0.f), 19.f);
        float pi0 = fminf(floorf(pq), 18.f);
        pidx[c] = (int)pi0; pww[c] = pq - pi0; pwm[c] = 1.f - pww[c];
        float vq = fminf(fmaxf(u*4.f, 0.f), 4.f);
        float vi0 = fminf(floorf(vq), 3.f);
        vidx[c] = (int)vi0; vww[c] = vq - vi0; vwm[c] = 1.f - vww[c];
    }
    float comb[64];
    for (int f = 0; f < 64; ++f) {
        const float fxv = lwm[0]*lx[f*512+lidx[0]] + lww[0]*lx[f*512+lidx[0]+1];
        const float fyv = lwm[1]*ly[f*512+lidx[1]] + lww[1]*ly[f*512+lidx[1]+1];
        const float fzv = lwm[2]*lz[f*512+lidx[2]] + lww[2]*lz[f*512+lidx[2]+1];
        const int bxy = f*400 + pidx[1]*20 + pidx[0];
        const float pxyv = pwm[1]*pwm[0]*pxy[bxy]    + pwm[1]*pww[0]*pxy[bxy+1]
                         + pww[1]*pwm[0]*pxy[bxy+20] + pww[1]*pww[0]*pxy[bxy+21];
        const int byz = f*400 + pidx[2]*20 + pidx[1];
        const float pyzv = pwm[2]*pwm[1]*pyz[byz]    + pwm[2]*pww[1]*pyz[byz+1]
                         + pww[2]*pwm[1]*pyz[byz+20] + pww[2]*pww[1]*pyz[byz+21];
        const int bzx = f*400 + pidx[0]*20 + pidx[2];
        const float pzxv = pwm[0]*pwm[2]*pzx[bzx]    + pwm[0]*pww[2]*pzx[bzx+1]
                         + pww[0]*pwm[2]*pzx[bzx+20] + pww[0]*pww[2]*pzx[bzx+21];
        const int bv = f*125 + (vidx[2]*5 + vidx[1])*5 + vidx[0];
        float vv = 0.f;
        for (int dz = 0; dz < 2; ++dz)
            for (int dy = 0; dy < 2; ++dy)
                for (int dx = 0; dx < 2; ++dx) {
                    const float w = (dz ? vww[2] : vwm[2]) * (dy ? vww[1] : vwm[1]) * (dx ? vww[0] : vwm[0]);
                    vv += w * vol[bv + dz*25 + dy*5 + dx];
                }
        comb[f] = fxv*fyv*fzv + pxyv*fzv + pyzv*fxv + pzxv*fyv + vv;
    }
    float o = b2[0];
    for (int gg = 0; gg < 64; ++gg) {
        float h = b1[gg];
        for (int f = 0; f < 64; ++f) h = fmaf(comb[f], w1[gg*64 + f], h);
        o = fmaf(fmaxf(h, 0.f), w2[gg], o);
    }
    out[n] = o;
}

extern "C" void kernel_launch(void* const* d_in, const int* in_sizes, int n_in,
                              void* d_out, int out_size, void* d_ws, size_t ws_size,
                              hipStream_t stream)
{
    const float* coords = (const float*)d_in[0];
    const float* lx  = (const float*)d_in[1];
    const float* ly  = (const float*)d_in[2];
    const float* lz  = (const float*)d_in[3];
    const float* pxy = (const float*)d_in[4];
    const float* pyz = (const float*)d_in[5];
    const float* pzx = (const float*)d_in[6];
    const float* vol = (const float*)d_in[7];
    const float* w1  = (const float*)d_in[8];
    const float* b1  = (const float*)d_in[9];
    const float* w2  = (const float*)d_in[10];
    const float* b2  = (const float*)d_in[11];
    float* out = (float*)d_out;
    if (ws_size >= (size_t)WS_TOTAL_BYTES) {
        u32* ws = (u32*)d_ws;
        ga_prep<<<dim3(350), dim3(256), 0, stream>>>(lx, ly, lz, pxy, pyz, pzx, vol, ws);
        ga_main<<<dim3(256), dim3(1024), 0, stream>>>(coords, w1, b1, w2, b2, ws, out);
    } else {
        ga_naive<<<dim3(4096), dim3(256), 0, stream>>>(coords, lx, ly, lz, pxy, pyz, pzx, vol,
                                                       w1, b1, w2, b2, out);
    }
}

// Round 14
// 176.012 us; speedup vs baseline: 2.1234x; 1.1096x over previous
//
#include <hip/hip_runtime.h>

typedef unsigned int u32;
typedef _Float16 half_t;
typedef half_t h2    __attribute__((ext_vector_type(2)));
typedef half_t f16x8 __attribute__((ext_vector_type(8)));
typedef float  f32x4 __attribute__((ext_vector_type(4)));
typedef float  f32x2 __attribute__((ext_vector_type(2)));
typedef __fp16 fp16v2 __attribute__((ext_vector_type(2)));

#define NPTS 1048576

// FINAL: this is the round-8 kernel restored verbatim -- the best measured
// configuration (ga_main 109.5us, total 177.4us, VALUBusy 67%).
// Closed-out experiment log:
// 1) __has_builtin(amdgcn) gating is false in the HOST pass -> silent naive
//    fallback (R1-2, 4.4x).  Never gate kernel defs / launch on it.
// 2) __launch_bounds__ 2nd arg is an allocator FLOOR: (1024,8) -> total spill
//    (R5, 4x).  (1024,4) compiles this body to 64 VGPR clean.
// 3) Divergent table reads must be LDS or iteration-ahead regs (R6: tables
//    from L2 -> latency-bound, 3x).
// 4) Allocator pins this body at 64 VGPR: f16-line prefetch spilled (R9,
//    WRITE +2MB) or sank to use (R10).  fp8 lines + 2-instr decode stay.
// 5) In-wave interleave {issue LDS batch N+1 | FMA batch N}: 123 -> 109.5us (R8).
// 6) Bank-conflict "fixes" both regressed: 132-B rows killed conflicts
//    (1.86e7->32) but broke 16-B alignment -> split b128s, 3x slower (R12);
//    136-B rows + b64 pairs doubled LDS ops (conflicts 3.2e7) and spilled
//    temps (R13, +13MB scratch).  R8's 1.86e7 conflict cycles ride the LDS
//    pipe largely in parallel with the 67%-busy VALU pipe -- already hidden.
// 7) Occupancy is LDS-capped at 16 waves/CU; raising it via no-LDS (R6),
//    fp8-planes-in-77KB (R7), or reg floors (R5) all lost more than gained.

#if defined(__has_builtin)
#if __has_builtin(__builtin_amdgcn_update_dpp)
#define HAS_DPP 1
#endif
#endif
#ifndef HAS_DPP
#define HAS_DPP 0
#endif

// ---------------------------------------------------------------------------
// workspace layout (dwords)
//   lines (fp8, tap-split): 3*511 rows x 32 dw (128 B/row)           49,056 dw
//   table image (copied verbatim to LDS):                            40,500 dw
//     planes xy,yz f16: 2*400 rows x 36 dw (144 B/row, 4 dw pad)     28,800 dw
//     volume    f16:      125 rows x 36 dw                            4,500 dw
//     plane zx fp8:       400 rows x 18 dw (72 B/row, 2 dw pad)       7,200 dw
// ---------------------------------------------------------------------------
#define WS_LINE_DW   49056
#define WS_TAB_DW    49056
#define TAB_VOL_DW   28800
#define TAB_PZ8_DW   33300
#define LDS_TOT_DW   40500
#define WS_TOTAL_DW  (WS_TAB_DW + LDS_TOT_DW)
#define WS_TOTAL_BYTES (WS_TOTAL_DW * 4)

// LDS byte offsets
#define LDS_VOL_B 115200      // 28800 dw * 4
#define LDS_PZ8_B 133200      // 33300 dw * 4

__device__ __forceinline__ u32 pkh(float a, float b) {
    union { h2 h; u32 u; } r;
    r.h = (h2){(half_t)a, (half_t)b};
    return r.u;
}
__device__ __forceinline__ h2 pkrtz(float a, float b) {
    union { fp16v2 f; h2 h; } r;
    r.f = __builtin_amdgcn_cvt_pkrtz(a, b);
    return r.h;
}
// broadcast halves of a packed pair; folds into VOP3P op_sel on consumers
__device__ __forceinline__ h2 lo2(h2 v) { return __builtin_shufflevector(v, v, 0, 0); }
__device__ __forceinline__ h2 hi2(h2 v) { return __builtin_shufflevector(v, v, 1, 1); }

// fp8 byte-pair (word selected by HI) -> f16 pair (exact: e4m3 subset of f16)
template<bool HI>
__device__ __forceinline__ h2 c8h(u32 s) {
    f32x2 e = __builtin_amdgcn_cvt_pk_f32_fp8((int)s, HI);
    return pkrtz(e.x, e.y);
}
#if HAS_DPP
template<int CTRL>
__device__ __forceinline__ float dpp_bfly(float v) {
    int t = __builtin_amdgcn_update_dpp(0, __float_as_int(v), CTRL, 0xF, 0xF, false);
    return v + __int_as_float(t);
}
#endif

union U4 { uint4 v; u32 s[4]; };
union UH { uint4 v; h2 h[4]; };

// ---------------------------------------------------------------------------
// Prep: fp8 tap-split lines + [planes|vol|pzx] LDS image in ws
// ---------------------------------------------------------------------------
__global__ __launch_bounds__(256) void ga_prep(
    const float* __restrict__ lx, const float* __restrict__ ly, const float* __restrict__ lz,
    const float* __restrict__ pxy, const float* __restrict__ pyz, const float* __restrict__ pzx,
    const float* __restrict__ vol, u32* __restrict__ ws)
{
    const int stride = gridDim.x * blockDim.x;
    for (int t = blockIdx.x * blockDim.x + threadIdx.x; t < WS_TOTAL_DW; t += stride) {
        if (t < WS_LINE_DW) {
            // fp8 lines, tap-split: dw d of row i0 = bytes (f0t0, f1t0, f0t1, f1t1)
            const int c  = t / 16352;           // 511*32
            const int r  = t - c * 16352;
            const int i0 = r >> 5;              // 0..510
            const int d  = r & 31;
            const float* L = (c == 0) ? lx : (c == 1) ? ly : lz;
            const int f0 = 2*d, f1 = 2*d + 1;
            int v = 0;
            v = __builtin_amdgcn_cvt_pk_fp8_f32(L[f0*512 + i0],     L[f1*512 + i0],     v, false);
            v = __builtin_amdgcn_cvt_pk_fp8_f32(L[f0*512 + i0 + 1], L[f1*512 + i0 + 1], v, true);
            ws[t] = (u32)v;
        } else {
            const int u = t - WS_TAB_DW;
            if (u < TAB_VOL_DW) {
                // planes xy,yz f16: [pp][row][36 dw] (4 dw pad)
                const int pp  = u / 14400;
                const int rr  = u - pp * 14400;
                const int row = rr / 36;
                const int d   = rr - row * 36;
                u32 v = 0;
                if (d < 32) {
                    const float* P = pp ? pyz : pxy;
                    const int f = 2*d;
                    v = pkh(P[f*400 + row], P[(f+1)*400 + row]);
                }
                ws[t] = v;
            } else if (u < TAB_PZ8_DW) {
                // volume f16: [vox][36 dw]
                const int r2  = u - TAB_VOL_DW;
                const int vox = r2 / 36;
                const int d   = r2 - vox * 36;
                u32 v = 0;
                if (d < 32) {
                    const int f = 2*d;
                    v = pkh(vol[f*125 + vox], vol[(f+1)*125 + vox]);
                }
                ws[t] = v;
            } else {
                // plane zx fp8: [row][18 dw] (2 dw pad)
                const int r2  = u - TAB_PZ8_DW;
                const int row = r2 / 18;
                const int d   = r2 - row * 18;
                u32 v = 0;
                if (d < 16) {
                    const int f0 = d * 4;
                    int dw = 0;
                    dw = __builtin_amdgcn_cvt_pk_fp8_f32(pzx[(f0+0)*400+row], pzx[(f0+1)*400+row], dw, false);
                    dw = __builtin_amdgcn_cvt_pk_fp8_f32(pzx[(f0+2)*400+row], pzx[(f0+3)*400+row], dw, true);
                    v = (u32)dw;
                }
                ws[t] = v;
            }
        }
    }
}

// line setup: byte base + lerp weights for one channel
__device__ __forceinline__ void lsetup(float v, int cbase, int fg16,
                                       int& la, float& wm, float& ww)
{
    const float u   = fmaf(v, 0.5f, 0.5f);
    const float pos = u * 511.f;
    const float fi  = fminf(floorf(pos), 510.f);   // clamp needed: u can round to 1.0
    la = cbase + ((int)fi) * 128 + fg16;
    ww = pos - fi;
    wm = 1.f - ww;
}

// ---------------------------------------------------------------------------
// Main: lane = (point p = lane&15, feature group fg = lane>>4).
// All tables in LDS (162 KB, 1 block/CU); lines fp8 from L2, depth-1 pipeline.
// cc body interleaves {load batch N+1} with {FMA batch N} to hide LDS latency
// within the wave.
// ---------------------------------------------------------------------------
__global__ __launch_bounds__(1024, 4) void ga_main(
    const float* __restrict__ coords,
    const float* __restrict__ w1,
    const float* __restrict__ b1,
    const float* __restrict__ w2,
    const float* __restrict__ b2,
    const u32* __restrict__ ws,
    float* __restrict__ out)
{
    __shared__ alignas(16) u32 sP[LDS_TOT_DW];   // 162,000 B
    const int tid = threadIdx.x;
    {
        const uint4* src = (const uint4*)(ws + WS_TAB_DW);
        uint4* dst = (uint4*)sP;
        #pragma unroll
        for (int i = 0; i < 10; ++i) {
            int idx = tid + i * 1024;
            if (idx < 10125) dst[idx] = src[idx];
        }
    }

    const int lane = tid & 63;
    const int wave = tid >> 6;       // 0..15
    const int p    = lane & 15;
    const int fg   = lane >> 4;      // 0..3
    const int fg16 = fg << 4;
    const int fg8  = fg << 3;
    const int wgbase = blockIdx.x << 12;   // 4096 points per workgroup

    // w1 B-fragments (f16)
    f16x8 wfrag[4][2];
    #pragma unroll
    for (int t = 0; t < 4; ++t) {
        #pragma unroll
        for (int h = 0; h < 2; ++h) {
            const float* src = w1 + ((16*t + p)*64 + h*32 + fg*8);
            f16x8 w;
            #pragma unroll
            for (int e = 0; e < 8; ++e) w[e] = (half_t)src[e];
            wfrag[t][h] = w;
        }
    }
    float b1v[4], w2v[4];
    #pragma unroll
    for (int t = 0; t < 4; ++t) { b1v[t] = b1[16*t + p]; w2v[t] = w2[16*t + p]; }
    const float b2v = b2[0];

    const char* wsb = (const char*)ws;
    const char* spb = (const char*)sP;

    // pipeline prologue: first point's coords, line setup, line loads in flight
    const int pt0 = wgbase + (wave << 4) + p;
    float cx = coords[3*pt0 + 0];
    float cy = coords[3*pt0 + 1];
    float cz = coords[3*pt0 + 2];
    int la0, la1, la2;
    float lwm[3], lww[3];
    lsetup(cx, 0,      fg16, la0, lwm[0], lww[0]);
    lsetup(cy, 65408,  fg16, la1, lwm[1], lww[1]);
    lsetup(cz, 130816, fg16, la2, lwm[2], lww[2]);
    U4 X0, X1, Y0, Y1, Z0, Z1;
    X0.v = *(const uint4*)(wsb + la0);
    X1.v = *(const uint4*)(wsb + la0 + 64);
    Y0.v = *(const uint4*)(wsb + la1);
    Y1.v = *(const uint4*)(wsb + la1 + 64);
    Z0.v = *(const uint4*)(wsb + la2);
    Z1.v = *(const uint4*)(wsb + la2 + 64);

    __syncthreads();

    for (int g = wave; g < 256; g += 16) {
        const int pbase = wgbase + (g << 4);
        const int gn = (g + 16 < 256) ? g + 16 : g;
        const int ptn = wgbase + (gn << 4) + p;
        const float nx = coords[3*ptn + 0];
        const float ny = coords[3*ptn + 1];
        const float nz = coords[3*ptn + 2];

        // ---- per-point plane/vol setup (line setup done last iteration) ----
        int pidx[3], vidx[3];
        float pww[3], pwm[3], vww[3], vwm[3];
        {
            const float cc3[3] = {cx, cy, cz};
            #pragma unroll
            for (int c = 0; c < 3; ++c) {
                const float u = fmaf(cc3[c], 0.5f, 0.5f);
                float pq  = u * 19.f;
                float pi0 = fminf(floorf(pq), 18.f);
                pidx[c] = (int)pi0; pww[c] = pq - pi0; pwm[c] = 1.f - pww[c];
                float vq  = u * 4.f;
                float vi0 = fminf(floorf(vq), 3.f);
                vidx[c] = (int)vi0; vww[c] = vq - vi0; vwm[c] = 1.f - vww[c];
            }
        }
        // one mad per table; all corners are compile-time ds offsets
        const int axy = (pidx[1]*20 + pidx[0]) * 144 + fg16;
        const int ayz = (pidx[2]*20 + pidx[1]) * 144 + (57600 + fg16);
        const int azx = (pidx[0]*20 + pidx[2]) * 72  + (LDS_PZ8_B + fg8);
        const int av  = ((vidx[2]*5 + vidx[1])*5 + vidx[0]) * 144 + (LDS_VOL_B + fg16);

        // packed f16 weights (lo2/hi2 broadcasts fold into op_sel)
        const h2 wl0 = pkrtz(lwm[0], lww[0]);
        const h2 wl1 = pkrtz(lwm[1], lww[1]);
        const h2 wl2 = pkrtz(lwm[2], lww[2]);
        const h2 wxy0 = pkrtz(pwm[1]*pwm[0], pwm[1]*pww[0]);
        const h2 wxy1 = pkrtz(pww[1]*pwm[0], pww[1]*pww[0]);
        const h2 wyz0 = pkrtz(pwm[2]*pwm[1], pwm[2]*pww[1]);
        const h2 wyz1 = pkrtz(pww[2]*pwm[1], pww[2]*pww[1]);
        const h2 wzx0 = pkrtz(pwm[0]*pwm[2], pwm[0]*pww[2]);
        const h2 wzx1 = pkrtz(pww[0]*pwm[2], pww[0]*pww[2]);
        const float wy0 = vwm[1]*vwm[0], wy1 = vwm[1]*vww[0];
        const float wy2 = vww[1]*vwm[0], wy3 = vww[1]*vww[0];
        const h2 wv0 = pkrtz(vwm[2]*wy0, vwm[2]*wy1);
        const h2 wv1 = pkrtz(vwm[2]*wy2, vwm[2]*wy3);
        const h2 wv2 = pkrtz(vww[2]*wy0, vww[2]*wy1);
        const h2 wv3 = pkrtz(vww[2]*wy2, vww[2]*wy3);

        h2 comb[2][4];
        #pragma unroll
        for (int cc = 0; cc < 2; ++cc) {
            const int co = cc * 64;
            // ---- (1) issue volume LDS reads ----
            UH V[8];
            #pragma unroll
            for (int dz = 0; dz < 2; ++dz)
                #pragma unroll
                for (int dy = 0; dy < 2; ++dy)
                    #pragma unroll
                    for (int dx = 0; dx < 2; ++dx)
                        V[dz*4+dy*2+dx].v =
                            *(const uint4*)(spb + av + (dz*25+dy*5+dx)*144 + co);
            // ---- (2) line lerps: register-only, covers the vol ds_reads ----
            const U4& LXc = cc ? X1 : X0;
            const U4& LYc = cc ? Y1 : Y0;
            const U4& LZc = cc ? Z1 : Z0;
            h2 fx[4], fy[4], fz[4];
            #pragma unroll
            for (int i = 0; i < 4; ++i) {
                fx[i] = c8h<false>(LXc.s[i])*lo2(wl0) + c8h<true>(LXc.s[i])*hi2(wl0);
                fy[i] = c8h<false>(LYc.s[i])*lo2(wl1) + c8h<true>(LYc.s[i])*hi2(wl1);
                fz[i] = c8h<false>(LZc.s[i])*lo2(wl2) + c8h<true>(LZc.s[i])*hi2(wl2);
            }
            #pragma unroll
            for (int j = 0; j < 4; ++j) comb[cc][j] = fx[j]*fy[j]*fz[j];
            // ---- (3) issue plane-xy LDS reads ----
            UH r0, r1, r2, r3;
            r0.v = *(const uint4*)(spb + axy + co);
            r1.v = *(const uint4*)(spb + axy + 144 + co);
            r2.v = *(const uint4*)(spb + axy + 2880 + co);
            r3.v = *(const uint4*)(spb + axy + 3024 + co);
            // ---- (4) volume FMAs: cover the xy ds_reads ----
            #pragma unroll
            for (int j = 0; j < 4; ++j) {
                h2 s = V[0].h[j]*lo2(wv0) + V[1].h[j]*hi2(wv0)
                     + V[2].h[j]*lo2(wv1) + V[3].h[j]*hi2(wv1);
                s += V[4].h[j]*lo2(wv2) + V[5].h[j]*hi2(wv2)
                   + V[6].h[j]*lo2(wv3) + V[7].h[j]*hi2(wv3);
                comb[cc][j] += s;
            }
            // ---- (5) issue plane-yz LDS reads ----
            UH s0, s1, s2, s3;
            s0.v = *(const uint4*)(spb + ayz + co);
            s1.v = *(const uint4*)(spb + ayz + 144 + co);
            s2.v = *(const uint4*)(spb + ayz + 2880 + co);
            s3.v = *(const uint4*)(spb + ayz + 3024 + co);
            // ---- (6) plane-xy FMAs: cover the yz ds_reads ----
            #pragma unroll
            for (int j = 0; j < 4; ++j) {
                h2 pa = r0.h[j]*lo2(wxy0) + r1.h[j]*hi2(wxy0)
                      + r2.h[j]*lo2(wxy1) + r3.h[j]*hi2(wxy1);
                comb[cc][j] += pa * fz[j];
            }
            // ---- (7) issue plane-zx (fp8) LDS reads ----
            const int czo = cc * 32;
            const uint2 q0 = *(const uint2*)(spb + azx + czo);
            const uint2 q1 = *(const uint2*)(spb + azx + 72 + czo);
            const uint2 q2 = *(const uint2*)(spb + azx + 1440 + czo);
            const uint2 q3 = *(const uint2*)(spb + azx + 1512 + czo);
            // ---- (8) plane-yz FMAs: cover the zx ds_reads ----
            #pragma unroll
            for (int j = 0; j < 4; ++j) {
                h2 pa = s0.h[j]*lo2(wyz0) + s1.h[j]*hi2(wyz0)
                      + s2.h[j]*lo2(wyz1) + s3.h[j]*hi2(wyz1);
                comb[cc][j] += pa * fx[j];
            }
            // ---- (9) plane-zx decode + FMAs ----
            {
                h2 pa0 = c8h<false>(q0.x)*lo2(wzx0) + c8h<false>(q1.x)*hi2(wzx0)
                       + c8h<false>(q2.x)*lo2(wzx1) + c8h<false>(q3.x)*hi2(wzx1);
                h2 pa1 = c8h<true >(q0.x)*lo2(wzx0) + c8h<true >(q1.x)*hi2(wzx0)
                       + c8h<true >(q2.x)*lo2(wzx1) + c8h<true >(q3.x)*hi2(wzx1);
                h2 pa2 = c8h<false>(q0.y)*lo2(wzx0) + c8h<false>(q1.y)*hi2(wzx0)
                       + c8h<false>(q2.y)*lo2(wzx1) + c8h<false>(q3.y)*hi2(wzx1);
                h2 pa3 = c8h<true >(q0.y)*lo2(wzx0) + c8h<true >(q1.y)*hi2(wzx0)
                       + c8h<true >(q2.y)*lo2(wzx1) + c8h<true >(q3.y)*hi2(wzx1);
                comb[cc][0] += pa0 * fy[0];
                comb[cc][1] += pa1 * fy[1];
                comb[cc][2] += pa2 * fy[2];
                comb[cc][3] += pa3 * fy[3];
            }
        }

        // ---- pipeline: next iteration's line setup + loads, issued early ----
        int nla0, nla1, nla2;
        float nlwm[3], nlww[3];
        lsetup(nx, 0,      fg16, nla0, nlwm[0], nlww[0]);
        lsetup(ny, 65408,  fg16, nla1, nlwm[1], nlww[1]);
        lsetup(nz, 130816, fg16, nla2, nlwm[2], nlww[2]);
        U4 NX0, NX1, NY0, NY1, NZ0, NZ1;
        NX0.v = *(const uint4*)(wsb + nla0);
        NX1.v = *(const uint4*)(wsb + nla0 + 64);
        NY0.v = *(const uint4*)(wsb + nla1);
        NY1.v = *(const uint4*)(wsb + nla1 + 64);
        NZ0.v = *(const uint4*)(wsb + nla2);
        NZ1.v = *(const uint4*)(wsb + nla2 + 64);

        // ---- MLP layer 1 via f16 MFMA; comb is already the A-fragment ----
        union AF { f16x8 v; h2 h[4]; } A0, A1;
        #pragma unroll
        for (int j = 0; j < 4; ++j) { A0.h[j] = comb[0][j]; A1.h[j] = comb[1][j]; }
        f32x4 acc0 = {0.f,0.f,0.f,0.f};
        f32x4 acc1 = {0.f,0.f,0.f,0.f};
        f32x4 acc2 = {0.f,0.f,0.f,0.f};
        f32x4 acc3 = {0.f,0.f,0.f,0.f};
        acc0 = __builtin_amdgcn_mfma_f32_16x16x32_f16(A0.v, wfrag[0][0], acc0, 0, 0, 0);
        acc0 = __builtin_amdgcn_mfma_f32_16x16x32_f16(A1.v, wfrag[0][1], acc0, 0, 0, 0);
        acc1 = __builtin_amdgcn_mfma_f32_16x16x32_f16(A0.v, wfrag[1][0], acc1, 0, 0, 0);
        acc1 = __builtin_amdgcn_mfma_f32_16x16x32_f16(A1.v, wfrag[1][1], acc1, 0, 0, 0);
        acc2 = __builtin_amdgcn_mfma_f32_16x16x32_f16(A0.v, wfrag[2][0], acc2, 0, 0, 0);
        acc2 = __builtin_amdgcn_mfma_f32_16x16x32_f16(A1.v, wfrag[2][1], acc2, 0, 0, 0);
        acc3 = __builtin_amdgcn_mfma_f32_16x16x32_f16(A0.v, wfrag[3][0], acc3, 0, 0, 0);
        acc3 = __builtin_amdgcn_mfma_f32_16x16x32_f16(A1.v, wfrag[3][1], acc3, 0, 0, 0);
        // layer 2: relu + dot with w2; reduce across the 16 C-layout columns
        float sr[4];
        #pragma unroll
        for (int r = 0; r < 4; ++r) {
            float s = fmaxf(acc0[r] + b1v[0], 0.f) * w2v[0];
            s = fmaf(fmaxf(acc1[r] + b1v[1], 0.f), w2v[1], s);
            s = fmaf(fmaxf(acc2[r] + b1v[2], 0.f), w2v[2], s);
            s = fmaf(fmaxf(acc3[r] + b1v[3], 0.f), w2v[3], s);
            sr[r] = s;
        }
#if HAS_DPP
        #pragma unroll
        for (int r = 0; r < 4; ++r) {
            float s = sr[r];
            s = dpp_bfly<0xB1>(s);    // quad_perm [1,0,3,2]  (xor 1)
            s = dpp_bfly<0x4E>(s);    // quad_perm [2,3,0,1]  (xor 2)
            s = dpp_bfly<0x141>(s);   // row_half_mirror      (xor 7 within 8)
            s = dpp_bfly<0x140>(s);   // row_mirror           (xor 15 within 16)
            sr[r] = s;
        }
#else
        #pragma unroll
        for (int m = 1; m <= 8; m <<= 1) {
            #pragma unroll
            for (int r = 0; r < 4; ++r) sr[r] += __shfl_xor(sr[r], m, 64);
        }
#endif
        if (p == 0) {
            float4 o;
            o.x = sr[0] + b2v;
            o.y = sr[1] + b2v;
            o.z = sr[2] + b2v;
            o.w = sr[3] + b2v;
            *(float4*)(out + pbase + (fg << 2)) = o;
        }
        // rotate pipeline state
        cx = nx; cy = ny; cz = nz;
        lwm[0] = nlwm[0]; lwm[1] = nlwm[1]; lwm[2] = nlwm[2];
        lww[0] = nlww[0]; lww[1] = nlww[1]; lww[2] = nlww[2];
        X0 = NX0; X1 = NX1; Y0 = NY0; Y1 = NY1; Z0 = NZ0; Z1 = NZ1;
    }
}

// ---------------------------------------------------------------------------
// Fallback (only if ws_size is too small): slow but correct, thread-per-point.
// ---------------------------------------------------------------------------
__global__ __launch_bounds__(256) void ga_naive(
    const float* __restrict__ coords,
    const float* __restrict__ lx, const float* __restrict__ ly, const float* __restrict__ lz,
    const float* __restrict__ pxy, const float* __restrict__ pyz, const float* __restrict__ pzx,
    const float* __restrict__ vol,
    const float* __restrict__ w1, const float* __restrict__ b1,
    const float* __restrict__ w2, const float* __restrict__ b2,
    float* __restrict__ out)
{
    const int n = blockIdx.x * blockDim.x + threadIdx.x;
    if (n >= NPTS) return;
    int lidx[3], pidx[3], vidx[3];
    float lww[3], lwm[3], pww[3], pwm[3], vww[3], vwm[3];
    for (int c = 0; c < 3; ++c) {
        const float cv = coords[3*n + c];
        const float u = (cv + 1.f)*0.5f;
        float pos = fminf(fmaxf(u*511.f, 0.f), 511.f);
        float i0 = fminf(floorf(pos), 510.f);
        lidx[c] = (int)i0; lww[c] = pos - i0; lwm[c] = 1.f - lww[c];
        float pq = fminf(fmaxf(u*19.f, 0.f), 19.f);
        float pi0 = fminf(floorf(pq), 18.f);
        pidx[c] = (int)pi0; pww[c] = pq - pi0; pwm[c] = 1.f - pww[c];
        float vq = fminf(fmaxf(u*4.f, 0.f), 4.f);
        float vi0 = fminf(floorf(vq), 3.f);
        vidx[c] = (int)vi0; vww[c] = vq - vi0; vwm[c] = 1.f - vww[c];
    }
    float comb[64];
    for (int f = 0; f < 64; ++f) {
        const float fxv = lwm[0]*lx[f*512+lidx[0]] + lww[0]*lx[f*512+lidx[0]+1];
        const float fyv = lwm[1]*ly[f*512+lidx[1]] + lww[1]*ly[f*512+lidx[1]+1];
        const float fzv = lwm[2]*lz[f*512+lidx[2]] + lww[2]*lz[f*512+lidx[2]+1];
        const int bxy = f*400 + pidx[1]*20 + pidx[0];
        const float pxyv = pwm[1]*pwm[0]*pxy[bxy]    + pwm[1]*pww[0]*pxy[bxy+1]
                         + pww[1]*pwm[0]*pxy[bxy+20] + pww[1]*pww[0]*pxy[bxy+21];
        const int byz = f*400 + pidx[2]*20 + pidx[1];
        const float pyzv = pwm[2]*pwm[1]*pyz[byz]    + pwm[2]*pww[1]*pyz[byz+1]
                         + pww[2]*pwm[1]*pyz[byz+20] + pww[2]*pww[1]*pyz[byz+21];
        const int bzx = f*400 + pidx[0]*20 + pidx[2];
        const float pzxv = pwm[0]*pwm[2]*pzx[bzx]    + pwm[0]*pww[2]*pzx[bzx+1]
                         + pww[0]*pwm[2]*pzx[bzx+20] + pww[0]*pww[2]*pzx[bzx+21];
        const int bv = f*125 + (vidx[2]*5 + vidx[1])*5 + vidx[0];
        float vv = 0.f;
        for (int dz = 0; dz < 2; ++dz)
            for (int dy = 0; dy < 2; ++dy)
                for (int dx = 0; dx < 2; ++dx) {
                    const float w = (dz ? vww[2] : vwm[2]) * (dy ? vww[1] : vwm[1]) * (dx ? vww[0] : vwm[0]);
                    vv += w * vol[bv + dz*25 + dy*5 + dx];
                }
        comb[f] = fxv*fyv*fzv + pxyv*fzv + pyzv*fxv + pzxv*fyv + vv;
    }
    float o = b2[0];
    for (int gg = 0; gg < 64; ++gg) {
        float h = b1[gg];
        for (int f = 0; f < 64; ++f) h = fmaf(comb[f], w1[gg*64 + f], h);
        o = fmaf(fmaxf(h, 0.f), w2[gg], o);
    }
    out[n] = o;
}

extern "C" void kernel_launch(void* const* d_in, const int* in_sizes, int n_in,
                              void* d_out, int out_size, void* d_ws, size_t ws_size,
                              hipStream_t stream)
{
    const float* coords = (const float*)d_in[0];
    const float* lx  = (const float*)d_in[1];
    const float* ly  = (const float*)d_in[2];
    const float* lz  = (const float*)d_in[3];
    const float* pxy = (const float*)d_in[4];
    const float* pyz = (const float*)d_in[5];
    const float* pzx = (const float*)d_in[6];
    const float* vol = (const float*)d_in[7];
    const float* w1  = (const float*)d_in[8];
    const float* b1  = (const float*)d_in[9];
    const float* w2  = (const float*)d_in[10];
    const float* b2  = (const float*)d_in[11];
    float* out = (float*)d_out;
    if (ws_size >= (size_t)WS_TOTAL_BYTES) {
        u32* ws = (u32*)d_ws;
        ga_prep<<<dim3(350), dim3(256), 0, stream>>>(lx, ly, lz, pxy, pyz, pzx, vol, ws);
        ga_main<<<dim3(256), dim3(1024), 0, stream>>>(coords, w1, b1, w2, b2, ws, out);
    } else {
        ga_naive<<<dim3(4096), dim3(256), 0, stream>>>(coords, lx, ly, lz, pxy, pyz, pzx, vol,
                                                       w1, b1, w2, b2, out);
    }
}